// Round 3
// baseline (336.832 us; speedup 1.0000x reference)
//
#include <hip/hip_runtime.h>
#include <stdint.h>

// EfficientSelfAttention on MI355X (gfx950). External I/O FP32; internals bf16
// MFMA. B=4, T=4096, D=1024, H=8, Dh=128. Scratch in __device__ globals.
// R9: gemm_kv schedule brought to the faithful m201 discipline:
//     - tile t+2 staged into the CURRENT buffer as regions free (A-ht0+B-ht0
//       after ph1, B-ht1 after ph2, A-ht1 after ph3)
//     - vmcnt(8) ONLY at ph4/ph8 (one full tile in flight, drained 4-7 phases
//       after issue) vs R8's 3 waits/tile at 1-2 phase lookahead
//     - prologue stages tiles 0+1, drains tile 0 only; peeled no-stage tail
//     Everything else (swizzle, epilogue, other kernels) unchanged from R8.

typedef unsigned short u16;
typedef __attribute__((ext_vector_type(8))) short bf16x8;
typedef __attribute__((ext_vector_type(4))) float f32x4;

// ------------------------------------------------------- device workspace
__device__ u16 g_WT[3][1024 * 1024];   // 6 MiB: WqT, WkT, WvT (bf16)
__device__ u16 g_xn[16777216];         // 32 MiB
__device__ u16 g_ekT[16777216];        // 32 MiB  [b][d][t]
__device__ u16 g_vvT[16777216];        // 32 MiB  [b][l][t]
__device__ float g_attp[8388608];      // 32 MiB  [kc*32+bh][d*128+l], 16 chunks
__device__ u16 g_attT[524288];         // 1 MiB   [bh][l*128+d]
__device__ float g_Z[4096];            //         [b*1024+d]

__device__ __forceinline__ float b2f(u16 u) {
  union { unsigned int i; float f; } c;
  c.i = ((unsigned int)u) << 16;
  return c.f;
}
__device__ __forceinline__ u16 f2b(float f) {
  union { float f; unsigned int i; } c;
  c.f = f;
  unsigned int r = c.i + 0x7fffu + ((c.i >> 16) & 1u);
  return (u16)(r >> 16);
}

__device__ __forceinline__ void gload16(const void* g, void* l) {
  __builtin_amdgcn_global_load_lds(
      reinterpret_cast<const __attribute__((address_space(1))) uint32_t*>(
          reinterpret_cast<uintptr_t>(g)),
      reinterpret_cast<__attribute__((address_space(3))) uint32_t*>(
          reinterpret_cast<uintptr_t>(l)),
      16, 0, 0);
}

// Stage 128x32 bf16 tile (row stride `stride` elems) into 8KB LDS [128][32].
// (used by gemm_att / gemm_qy — unchanged)
__device__ __forceinline__ void stage128x32(const u16* g, int stride, char* lds,
                                            int wave, int lane) {
  const int r = wave * 32 + (lane >> 2);
  const int cb = (lane & 3) * 16;
  const char* gp = (const char*)g;
  gload16(gp + (size_t)r * stride * 2 + cb, lds + wave * 2048);
  gload16(gp + (size_t)(r + 16) * stride * 2 + cb, lds + wave * 2048 + 1024);
}

// A/B fragment from [128][32] LDS tile: row `row`, k = (lane>>4)*8 .. +7
__device__ __forceinline__ bf16x8 frag_ld(const char* lds, int row, int lane) {
  return *(const bf16x8*)(lds + row * 64 + ((lane >> 4) * 16));
}

// 16 MFMA on one staged 128x32 A/B tile pair (gemm_att / gemm_qy).
__device__ __forceinline__ void tile_mfma(const char* As, const char* Bs,
                                          f32x4 (&acc)[4][4], int wm, int wn,
                                          int lane) {
  bf16x8 af[4], bfr[4];
#pragma unroll
  for (int i = 0; i < 4; i++) af[i] = frag_ld(As, wm * 64 + i * 16 + (lane & 15), lane);
#pragma unroll
  for (int j = 0; j < 4; j++) bfr[j] = frag_ld(Bs, wn * 64 + j * 16 + (lane & 15), lane);
#pragma unroll
  for (int i = 0; i < 4; i++)
#pragma unroll
    for (int j = 0; j < 4; j++)
      acc[i][j] = __builtin_amdgcn_mfma_f32_16x16x32_bf16(af[i], bfr[j], acc[i][j], 0, 0, 0);
}

// ---------------- 256^2 8-phase helpers (gemm_kv) ----------------
// [256][64]-bf16 LDS tile, 128B rows. Chunk-XOR swizzle: 16B-chunk slot s of
// row r holds global chunk (s ^ (r&7)). Stage: linear LDS dest (required by
// global_load_lds) + inverse-swizzled per-lane GLOBAL source. Read: swizzled
// ds_read address. Same involution on both sides (rule #21).
// Half-tiles defined by the READ pattern:
//   A-ht(h) = rows {r: (r>>6)&1 == h}  (quad rh reads rows wm*128+rh*64..+63)
//   B-ht(h) = rows {r: (r>>5)&1 == h}  (quad ch reads rows wn*64+ch*32..+31)
__device__ __forceinline__ void stageA256(char* buf, const u16* gsrc, int h,
                                          int wave, int lane) {
#pragma unroll
  for (int i = 0; i < 2; i++) {
    const int ib = i * 64 + wave * 8;  // idx base (wave-uniform)
    const int rowb = (ib & 63) | ((ib & 64) << 1) | (h << 6);
    const int row = rowb + (lane >> 3);
    const int cc = (lane & 7) ^ (row & 7);  // inverse-swizzled source chunk
    gload16((const char*)gsrc + ((size_t)row * 1024 + cc * 8) * 2,
            buf + rowb * 128);
  }
}
__device__ __forceinline__ void stageB256(char* buf, const u16* gsrc, int h,
                                          int wave, int lane) {
#pragma unroll
  for (int i = 0; i < 2; i++) {
    const int ib = i * 64 + wave * 8;
    const int rowb = (ib & 31) | ((ib & 96) << 1) | (h << 5);
    const int row = rowb + (lane >> 3);
    const int cc = (lane & 7) ^ (row & 7);
    gload16((const char*)gsrc + ((size_t)row * 1024 + cc * 8) * 2,
            buf + rowb * 128);
  }
}
// frag read: row R (includes lane&15), k-step ks: global chunk = ks*4 + q
__device__ __forceinline__ bf16x8 fragS(const char* buf, int R, int ks, int lane) {
  const int q = lane >> 4;
  return *(const bf16x8*)(buf + R * 128 + ((((ks << 2) + q) ^ (R & 7)) << 4));
}

// 4 phases = one K-tile on (Ab,Bb), staging tile t+2 into the SAME buffers as
// regions free. WAIT: vmcnt count at ph4 (-1 = none). ST: staging enabled.
// ph1 quad(0,0): read A-ht0 + B-ht0      ; no stage
// ph2 quad(0,1): read B-ht1              ; stage A-ht0(t+2) + B-ht0(t+2)
// ph3 quad(1,1): read A-ht1              ; stage B-ht1(t+2)
// ph4 quad(1,0): regs only               ; stage A-ht1(t+2) ; vmcnt(WAIT)
template<int WAIT, bool ST>
__device__ __forceinline__ void kv_4ph(char* Ab, char* Bb, const u16* Agn,
                                       const u16* Bgn, f32x4 (&acc)[8][4],
                                       int wave, int lane, int wm, int wn) {
  bf16x8 a[4][2], b0[2][2], b1[2][2];

  // ---- phase 1: quad(0,0) ----
#pragma unroll
  for (int rf = 0; rf < 4; rf++) {
    const int R = wm * 128 + rf * 16 + (lane & 15);
#pragma unroll
    for (int ks = 0; ks < 2; ks++) a[rf][ks] = fragS(Ab, R, ks, lane);
  }
#pragma unroll
  for (int cf = 0; cf < 2; cf++) {
    const int R = wn * 64 + cf * 16 + (lane & 15);
#pragma unroll
    for (int ks = 0; ks < 2; ks++) b0[cf][ks] = fragS(Bb, R, ks, lane);
  }
  __builtin_amdgcn_s_barrier();
  asm volatile("s_waitcnt lgkmcnt(0)" ::: "memory");
  __builtin_amdgcn_sched_barrier(0);
  __builtin_amdgcn_s_setprio(1);
#pragma unroll
  for (int rf = 0; rf < 4; rf++)
#pragma unroll
    for (int cf = 0; cf < 2; cf++)
#pragma unroll
      for (int ks = 0; ks < 2; ks++)
        acc[rf][cf] = __builtin_amdgcn_mfma_f32_16x16x32_bf16(
            a[rf][ks], b0[cf][ks], acc[rf][cf], 0, 0, 0);
  __builtin_amdgcn_s_setprio(0);
  __builtin_amdgcn_s_barrier();
  __builtin_amdgcn_sched_barrier(0);

  // ---- phase 2: quad(0,1) ----
#pragma unroll
  for (int cf = 0; cf < 2; cf++) {
    const int R = wn * 64 + 32 + cf * 16 + (lane & 15);
#pragma unroll
    for (int ks = 0; ks < 2; ks++) b1[cf][ks] = fragS(Bb, R, ks, lane);
  }
  if constexpr (ST) {
    stageA256(Ab, Agn, 0, wave, lane);   // into region read-retired at ph1
    stageB256(Bb, Bgn, 0, wave, lane);
  }
  __builtin_amdgcn_s_barrier();
  asm volatile("s_waitcnt lgkmcnt(0)" ::: "memory");
  __builtin_amdgcn_sched_barrier(0);
  __builtin_amdgcn_s_setprio(1);
#pragma unroll
  for (int rf = 0; rf < 4; rf++)
#pragma unroll
    for (int cf = 0; cf < 2; cf++)
#pragma unroll
      for (int ks = 0; ks < 2; ks++)
        acc[rf][2 + cf] = __builtin_amdgcn_mfma_f32_16x16x32_bf16(
            a[rf][ks], b1[cf][ks], acc[rf][2 + cf], 0, 0, 0);
  __builtin_amdgcn_s_setprio(0);
  __builtin_amdgcn_s_barrier();
  __builtin_amdgcn_sched_barrier(0);

  // ---- phase 3: quad(1,1) ----
#pragma unroll
  for (int rf = 0; rf < 4; rf++) {
    const int R = wm * 128 + 64 + rf * 16 + (lane & 15);
#pragma unroll
    for (int ks = 0; ks < 2; ks++) a[rf][ks] = fragS(Ab, R, ks, lane);
  }
  if constexpr (ST) stageB256(Bb, Bgn, 1, wave, lane);  // read-retired at ph2
  __builtin_amdgcn_s_barrier();
  asm volatile("s_waitcnt lgkmcnt(0)" ::: "memory");
  __builtin_amdgcn_sched_barrier(0);
  __builtin_amdgcn_s_setprio(1);
#pragma unroll
  for (int rf = 0; rf < 4; rf++)
#pragma unroll
    for (int cf = 0; cf < 2; cf++)
#pragma unroll
      for (int ks = 0; ks < 2; ks++)
        acc[4 + rf][2 + cf] = __builtin_amdgcn_mfma_f32_16x16x32_bf16(
            a[rf][ks], b1[cf][ks], acc[4 + rf][2 + cf], 0, 0, 0);
  __builtin_amdgcn_s_setprio(0);
  __builtin_amdgcn_s_barrier();
  __builtin_amdgcn_sched_barrier(0);

  // ---- phase 4: quad(1,0) — register-only ----
  if constexpr (ST) stageA256(Ab, Agn, 1, wave, lane);  // read-retired at ph3
  if constexpr (WAIT == 8) {
    asm volatile("s_waitcnt vmcnt(8)" ::: "memory");
  } else if constexpr (WAIT == 0) {
    asm volatile("s_waitcnt vmcnt(0)" ::: "memory");
  }
  __builtin_amdgcn_s_barrier();
  __builtin_amdgcn_s_setprio(1);
#pragma unroll
  for (int rf = 0; rf < 4; rf++)
#pragma unroll
    for (int cf = 0; cf < 2; cf++)
#pragma unroll
      for (int ks = 0; ks < 2; ks++)
        acc[4 + rf][cf] = __builtin_amdgcn_mfma_f32_16x16x32_bf16(
            a[rf][ks], b0[cf][ks], acc[4 + rf][cf], 0, 0, 0);
  __builtin_amdgcn_s_setprio(0);
  __builtin_amdgcn_s_barrier();
  __builtin_amdgcn_sched_barrier(0);
}

// ---------------------------- prep: LN (blocks 0..16383) + W transpose (rest)
__global__ __launch_bounds__(256) void prep_kernel(const float* __restrict__ x,
                                                   const float* __restrict__ gamma,
                                                   const float* __restrict__ beta,
                                                   const float* __restrict__ wq,
                                                   const float* __restrict__ wk,
                                                   const float* __restrict__ wv) {
  __shared__ float ls[4], ls2[4];
  __shared__ u16 tile[32][33];
  const int bid = blockIdx.x;
  const int tid = threadIdx.x;
  if (bid < 16384) {
    if (bid < 16) g_Z[bid * 256 + tid] = 0.0f;  // per-launch Z reset
    const int wave = tid >> 6, lane = tid & 63;
    const float* xr = x + (size_t)bid * 1024;
    float4 u = ((const float4*)xr)[tid];
    float v0 = u.x, v1 = u.y, v2 = u.z, v3 = u.w;
    float s = v0 + v1 + v2 + v3;
    float s2 = v0 * v0 + v1 * v1 + v2 * v2 + v3 * v3;
#pragma unroll
    for (int off = 32; off > 0; off >>= 1) {
      s += __shfl_down(s, off);
      s2 += __shfl_down(s2, off);
    }
    if (lane == 0) { ls[wave] = s; ls2[wave] = s2; }
    __syncthreads();
    s = ls[0] + ls[1] + ls[2] + ls[3];
    s2 = ls2[0] + ls2[1] + ls2[2] + ls2[3];
    const float mu = s * (1.0f / 1024.0f);
    const float var = fmaxf(s2 * (1.0f / 1024.0f) - mu * mu, 0.0f);
    const float rstd = rsqrtf(var + 1e-5f);
    float4 g4 = ((const float4*)gamma)[tid];
    float4 be = ((const float4*)beta)[tid];
    ushort4 o;
    o.x = f2b((v0 - mu) * rstd * g4.x + be.x);
    o.y = f2b((v1 - mu) * rstd * g4.y + be.y);
    o.z = f2b((v2 - mu) * rstd * g4.z + be.z);
    o.w = f2b((v3 - mu) * rstd * g4.w + be.w);
    *(ushort4*)(g_xn + (size_t)bid * 1024 + tid * 4) = o;
  } else {
    const int id = bid - 16384;
    const int which = id >> 10;
    const int rem = id & 1023;
    const float* src = (which == 0) ? wq : (which == 1) ? wk : wv;
    u16* dst = g_WT[which];
    const int tx = tid & 31;
    const int ty = tid >> 5;
    const int c0 = (rem & 31) * 32, r0 = (rem >> 5) * 32;
#pragma unroll
    for (int i = 0; i < 4; i++)
      tile[ty + i * 8][tx] = f2b(src[(size_t)(r0 + ty + i * 8) * 1024 + c0 + tx]);
    __syncthreads();
#pragma unroll
    for (int i = 0; i < 4; i++)
      dst[(size_t)(c0 + ty + i * 8) * 1024 + r0 + tx] = tile[tx][ty + i * 8];
  }
}

// --------------------------------------------------------------- K/V GEMM
// 256^2 tile, 8-phase counted-vmcnt schedule (m201 discipline). Grid 512 =
// 64 m-tiles x 8 n-variants (4 n0 per z x 2 z). XCD swizzle: c=L&7 ->
// m-tile = c + 8*(L>>6); the 8 n-variants of one m-tile are consecutive L on
// one XCD (share A-slab).
// z=0: ekT[b][d][t] = (m>0.5) ? exp(xn@Wk^T + bk) : 0   (+ fused Z row-sums)
// z=1: vvT[b][l][t] = (xn@Wv^T + bv) * m
__global__ __launch_bounds__(512, 2) void gemm_kv(const float* __restrict__ bk,
                                                  const float* __restrict__ bv,
                                                  const float* __restrict__ mask) {
  __shared__ __align__(16) char smem[131072];
  const int tid = threadIdx.x, wave = tid >> 6, lane = tid & 63;
  const int L = blockIdx.x;
  const int mt = (L & 7) + 8 * (L >> 6);
  const int nt = (L >> 3) & 7;
  const int n0 = (nt & 3) * 256;
  const int z = nt >> 2;
  const int m0 = mt * 256;
  const u16* wt = z ? g_WT[2] : g_WT[1];
  const float* bias = z ? bv : bk;
  u16* outT = z ? g_vvT : g_ekT;
  const int b = m0 >> 12;
  const int t0 = m0 & 4095;
  const int wm = wave >> 2, wn = wave & 3;
  const u16* Ag = g_xn + (size_t)m0 * 1024;
  const u16* Bg = wt + (size_t)n0 * 1024;

  char* A0 = smem;
  char* A1 = smem + 32768;
  char* B0 = smem + 65536;
  char* B1 = smem + 98304;

  f32x4 zero = {0.f, 0.f, 0.f, 0.f};
  f32x4 acc[8][4];
#pragma unroll
  for (int i = 0; i < 8; i++)
#pragma unroll
    for (int j = 0; j < 4; j++) acc[i][j] = zero;

  // prologue: stage tiles 0 (buf0) and 1 (buf1); drain ONLY tile 0 (8 loads),
  // tile 1's 8 loads stay in flight until iter-0 ph4's vmcnt(8).
  stageA256(A0, Ag, 0, wave, lane);
  stageA256(A0, Ag, 1, wave, lane);
  stageB256(B0, Bg, 0, wave, lane);
  stageB256(B0, Bg, 1, wave, lane);
  stageA256(A1, Ag + 64, 0, wave, lane);
  stageA256(A1, Ag + 64, 1, wave, lane);
  stageB256(B1, Bg + 64, 0, wave, lane);
  stageB256(B1, Bg + 64, 1, wave, lane);
  asm volatile("s_waitcnt vmcnt(8)" ::: "memory");
  __builtin_amdgcn_s_barrier();

#pragma unroll 1
  for (int t = 0; t < 14; t += 2) {
    kv_4ph<8, true>(A0, B0, Ag + (t + 2) * 64, Bg + (t + 2) * 64, acc, wave,
                    lane, wm, wn);
    kv_4ph<8, true>(A1, B1, Ag + (t + 3) * 64, Bg + (t + 3) * 64, acc, wave,
                    lane, wm, wn);
  }
  // tail: tiles 14,15 — no staging; drain remaining (tile 15) at first ph4.
  kv_4ph<0, false>(A0, B0, Ag, Bg, acc, wave, lane, wm, wn);
  kv_4ph<-1, false>(A1, B1, Ag, Bg, acc, wave, lane, wm, wn);

  // epilogue: bias + mask/exp, fused zrow, transpose via swizzled LDS, store.
  u16* tT = (u16*)smem;
  float fsum[4] = {0.f, 0.f, 0.f, 0.f};
#pragma unroll
  for (int rf = 0; rf < 8; rf++)
#pragma unroll
    for (int r = 0; r < 4; r++) {
      const int tok = wm * 128 + rf * 16 + (lane >> 4) * 4 + r;
      const float mv = mask[m0 + tok];
#pragma unroll
      for (int cf = 0; cf < 4; cf++) {
        const int feat = wn * 64 + cf * 16 + (lane & 15);
        const float aV = acc[rf][cf][r] + bias[n0 + feat];
        float o;
        if (z)
          o = aV * mv;
        else
          o = (mv > 0.5f) ? __expf(fminf(aV, 30.0f)) : 0.0f;
        const u16 ob = f2b(o);
        tT[feat * 256 + ((((tok >> 3) ^ (feat & 7)) << 3) | (tok & 7))] = ob;
        if (!z) fsum[cf] += b2f(ob);  // sum rounded values == zrow semantics
      }
    }
  if (!z) {
#pragma unroll
    for (int cf = 0; cf < 4; cf++) {
      float s = fsum[cf];
      s += __shfl_xor(s, 16);
      s += __shfl_xor(s, 32);
      if (lane < 16)
        atomicAdd(&g_Z[b * 1024 + n0 + wn * 64 + cf * 16 + lane], s);
    }
  }
  __syncthreads();
  const size_t gbase = (size_t)b * (1024 * 4096) + (size_t)n0 * 4096 + t0;
#pragma unroll
  for (int u = 0; u < 16; u++) {
    const int id = u * 512 + tid;
    const int feat = id >> 5, c = id & 31;
    uint4 val = *(const uint4*)&tT[feat * 256 + ((c ^ (feat & 7)) << 3)];
    *(uint4*)(outT + gbase + (size_t)feat * 4096 + c * 8) = val;
  }
}

// ------------------------------------------------------------- att GEMM
// attp[kc][bh][d][l] = sum_{t in 256-chunk kc} ekT[b][h*128+d][t]*vvT[b][h*128+l][t]
__global__ __launch_bounds__(256) void gemm_att() {
  __shared__ __align__(16) char smem[32768];
  char* A0 = smem;
  char* B0 = smem + 8192;
  char* A1 = smem + 16384;
  char* B1 = smem + 24576;
  const int tid = threadIdx.x, wave = tid >> 6, lane = tid & 63;
  const int kc = blockIdx.x;  // 0..15
  const int bh = blockIdx.y;  // 0..31
  const int b = bh >> 3, h = bh & 7;
  const size_t base = (size_t)b * (1024 * 4096) + (size_t)(h * 128) * 4096;
  const int wm = wave & 1, wn = wave >> 1;
  const u16* Ag = g_ekT + base + kc * 256;
  const u16* Bg = g_vvT + base + kc * 256;

  f32x4 zero = {0.f, 0.f, 0.f, 0.f};
  f32x4 acc[4][4];
#pragma unroll
  for (int i = 0; i < 4; i++)
#pragma unroll
    for (int j = 0; j < 4; j++) acc[i][j] = zero;

  stage128x32(Ag, 4096, A0, wave, lane);
  stage128x32(Bg, 4096, B0, wave, lane);
  __syncthreads();
  for (int kt = 0; kt < 256; kt += 64) {
    stage128x32(Ag + kt + 32, 4096, A1, wave, lane);
    stage128x32(Bg + kt + 32, 4096, B1, wave, lane);
    tile_mfma(A0, B0, acc, wm, wn, lane);
    __syncthreads();
    if (kt + 64 < 256) {
      stage128x32(Ag + kt + 64, 4096, A0, wave, lane);
      stage128x32(Bg + kt + 64, 4096, B0, wave, lane);
    }
    tile_mfma(A1, B1, acc, wm, wn, lane);
    __syncthreads();
  }

  float* op = g_attp + ((size_t)(kc * 32 + bh)) * 16384;
#pragma unroll
  for (int i = 0; i < 4; i++)
#pragma unroll
    for (int r = 0; r < 4; r++) {
      const int row = wm * 64 + i * 16 + (lane >> 4) * 4 + r;
#pragma unroll
      for (int j = 0; j < 4; j++) {
        const int col = wn * 64 + j * 16 + (lane & 15);
        op[row * 128 + col] = acc[i][j][r];
      }
    }
}

// ------------------------------------- reduce partials, /Z, store attT[bh][l][d]
__global__ __launch_bounds__(256) void attnorm_kernel() {
  const int bh = blockIdx.x;
  const int b = bh >> 3, h = bh & 7;
  const int tid = threadIdx.x;
  __shared__ float Zl[128];
  if (tid < 128) Zl[tid] = fmaxf(g_Z[b * 1024 + h * 128 + tid], 1e-30f);
  __syncthreads();
  const int i0 = blockIdx.y * 2048;
  for (int i = i0 + tid; i < i0 + 2048; i += 256) {
    const int d = i >> 7, l = i & 127;
    float s = 0.f;
#pragma unroll
    for (int c = 0; c < 16; c++) s += g_attp[((size_t)(c * 32 + bh)) * 16384 + i];
    g_attT[(size_t)bh * 16384 + l * 128 + d] = f2b(s / Zl[d]);
  }
}

// ---------------------------------------------------------- fused q + y
// 1-D grid 1024, XCD swizzle: c=L&7, k=L>>3; m0 = c+8*(k>>3); h = k&7.
__global__ __launch_bounds__(256) void gemm_qy(const float* __restrict__ bq,
                                               const float* __restrict__ x,
                                               float* __restrict__ out) {
  __shared__ __align__(16) char smem[51200];
  __shared__ float zqp[2][128];
  char* A0 = smem;
  char* B0 = smem + 8192;
  char* A1 = smem + 16384;
  char* B1 = smem + 24576;
  u16* qs = (u16*)smem;            // [token][feature] 128x136 padded (34816B)
  char* C0 = smem + 34816;         // phase-2 attT tile dbuf
  char* C1 = smem + 43008;
  const int tid = threadIdx.x, wave = tid >> 6, lane = tid & 63;
  const int L = blockIdx.x;
  const int c = L & 7;
  const int k = L >> 3;              // 0..127
  const int h = k & 7;               // head
  const int m0 = (c + 8 * (k >> 3)) * 128;  // token block, m0%8 == XCD
  const int b = m0 >> 12;
  const int bh = b * 8 + h;
  const int wm = wave & 1, wn = wave >> 1;
  const u16* Ag = g_xn + (size_t)m0 * 1024;
  const u16* Bg = g_WT[0] + (size_t)(h * 128) * 1024;
  const u16* Cg = g_attT + (size_t)bh * 16384;

  f32x4 zero = {0.f, 0.f, 0.f, 0.f};
  f32x4 acc[4][4];
#pragma unroll
  for (int i = 0; i < 4; i++)
#pragma unroll
    for (int j = 0; j < 4; j++) acc[i][j] = zero;

  // phase 1: q = xn @ WqT[head rows], 2-phase pipelined
  stage128x32(Ag, 1024, A0, wave, lane);
  stage128x32(Bg, 1024, B0, wave, lane);
  __syncthreads();
  for (int k0 = 0; k0 < 1024; k0 += 64) {
    stage128x32(Ag + k0 + 32, 1024, A1, wave, lane);
    stage128x32(Bg + k0 + 32, 1024, B1, wave, lane);
    tile_mfma(A0, B0, acc, wm, wn, lane);
    __syncthreads();
    if (k0 + 64 < 1024) {
      stage128x32(Ag + k0 + 64, 1024, A0, wave, lane);
      stage128x32(Bg + k0 + 64, 1024, B0, wave, lane);
    }
    tile_mfma(A1, B1, acc, wm, wn, lane);
    __syncthreads();
  }

  // prefetch phase-2 B tile 0 now; latency hides under epilogue-1 VALU work
  stage128x32(Cg, 128, C0, wave, lane);

  // epilogue 1: exp (clamped), store to qs, row-sums
#pragma unroll
  for (int i = 0; i < 4; i++)
#pragma unroll
    for (int r = 0; r < 4; r++) {
      const int rowl = wm * 64 + i * 16 + (lane >> 4) * 4 + r;
      float rs = 0.f;
#pragma unroll
      for (int j = 0; j < 4; j++) {
        const int coll = wn * 64 + j * 16 + (lane & 15);
        const float e = __expf(fminf(acc[i][j][r] + bq[h * 128 + coll], 30.0f));
        qs[rowl * 136 + coll] = f2b(e);
        rs += e;
      }
      rs += __shfl_xor(rs, 1);
      rs += __shfl_xor(rs, 2);
      rs += __shfl_xor(rs, 4);
      rs += __shfl_xor(rs, 8);
      if ((lane & 15) == 0) zqp[wn][rowl] = rs;
    }
  __syncthreads();  // qs visible; C0 prefetch drained

  // phase 2: y = qs @ attT[bh]^T  (K = 128), B double-buffered
  f32x4 acc2[4][4];
#pragma unroll
  for (int i = 0; i < 4; i++)
#pragma unroll
    for (int j = 0; j < 4; j++) acc2[i][j] = zero;

  for (int k0 = 0; k0 < 128; k0 += 64) {
    stage128x32(Cg + k0 + 32, 128, C1, wave, lane);
    {
      bf16x8 af[4], bfr[4];
#pragma unroll
      for (int i = 0; i < 4; i++)
        af[i] = *(const bf16x8*)&qs[(wm * 64 + i * 16 + (lane & 15)) * 136 + k0 + (lane >> 4) * 8];
#pragma unroll
      for (int j = 0; j < 4; j++) bfr[j] = frag_ld(C0, wn * 64 + j * 16 + (lane & 15), lane);
#pragma unroll
      for (int i = 0; i < 4; i++)
#pragma unroll
        for (int j = 0; j < 4; j++)
          acc2[i][j] = __builtin_amdgcn_mfma_f32_16x16x32_bf16(af[i], bfr[j], acc2[i][j], 0, 0, 0);
    }
    __syncthreads();
    if (k0 + 64 < 128) stage128x32(Cg + k0 + 64, 128, C0, wave, lane);
    {
      bf16x8 af[4], bfr[4];
#pragma unroll
      for (int i = 0; i < 4; i++)
        af[i] = *(const bf16x8*)&qs[(wm * 64 + i * 16 + (lane & 15)) * 136 + k0 + 32 + (lane >> 4) * 8];
#pragma unroll
      for (int j = 0; j < 4; j++) bfr[j] = frag_ld(C1, wn * 64 + j * 16 + (lane & 15), lane);
#pragma unroll
      for (int i = 0; i < 4; i++)
#pragma unroll
        for (int j = 0; j < 4; j++)
          acc2[i][j] = __builtin_amdgcn_mfma_f32_16x16x32_bf16(af[i], bfr[j], acc2[i][j], 0, 0, 0);
    }
    __syncthreads();
  }

  // epilogue 2: out = x + y / Zq  (fp32)
#pragma unroll
  for (int i = 0; i < 4; i++)
#pragma unroll
    for (int r = 0; r < 4; r++) {
      const int rowl = wm * 64 + i * 16 + (lane >> 4) * 4 + r;
      const float zq = fmaxf(zqp[0][rowl] + zqp[1][rowl], 1e-30f);
      const size_t n = (size_t)m0 + rowl;
#pragma unroll
      for (int j = 0; j < 4; j++) {
        const int coll = wn * 64 + j * 16 + (lane & 15);
        const size_t idx = n * 1024 + h * 128 + coll;
        out[idx] = x[idx] + acc2[i][j][r] / zq;
      }
    }
}

// ----------------------------------------------------------------- launch
extern "C" void kernel_launch(void* const* d_in, const int* in_sizes, int n_in,
                              void* d_out, int out_size, void* d_ws, size_t ws_size,
                              hipStream_t stream) {
  const float* x = (const float*)d_in[0];
  const float* mask = (const float*)d_in[1];
  const float* Wq = (const float*)d_in[2];
  const float* bq = (const float*)d_in[3];
  const float* Wk = (const float*)d_in[4];
  const float* bk = (const float*)d_in[5];
  const float* Wv = (const float*)d_in[6];
  const float* bv = (const float*)d_in[7];
  const float* gamma = (const float*)d_in[8];
  const float* beta = (const float*)d_in[9];
  float* out = (float*)d_out;
  (void)d_ws; (void)ws_size;

  prep_kernel<<<dim3(16384 + 3072), 256, 0, stream>>>(x, gamma, beta, Wq, Wk, Wv);
  gemm_kv<<<dim3(512), 512, 0, stream>>>(bk, bv, mask);
  gemm_att<<<dim3(16, 32), 256, 0, stream>>>();
  attnorm_kernel<<<dim3(32, 8), 256, 0, stream>>>();
  gemm_qy<<<dim3(1024), 256, 0, stream>>>(bq, x, out);
}

// Round 5
// 331.633 us; speedup vs baseline: 1.0157x; 1.0157x over previous
//
#include <hip/hip_runtime.h>
#include <stdint.h>

// EfficientSelfAttention on MI355X (gfx950). External I/O FP32; internals bf16
// MFMA. B=4, T=4096, D=1024, H=8, Dh=128. Scratch in __device__ globals.
// R11: fixes R10's gemm_qy phase-2 head bug — the A-fragment chunk index was
//      missing the per-head offset (hl<<4), so head-1 waves read head-0's P.
//      Everything else identical to R10: gemm_kv on the R8 8-phase schedule,
//      gemm_qy as a single 256-block 256^2 8-phase kernel (ph1 K=1024, ph2
//      K=128 with A from swizzled qs in LDS and B from L2-hot global attT).

typedef unsigned short u16;
typedef __attribute__((ext_vector_type(8))) short bf16x8;
typedef __attribute__((ext_vector_type(4))) float f32x4;

// ------------------------------------------------------- device workspace
__device__ u16 g_WT[3][1024 * 1024];   // 6 MiB: WqT, WkT, WvT (bf16)
__device__ u16 g_xn[16777216];         // 32 MiB
__device__ u16 g_ekT[16777216];        // 32 MiB  [b][d][t]
__device__ u16 g_vvT[16777216];        // 32 MiB  [b][l][t]
__device__ float g_attp[8388608];      // 32 MiB  [kc*32+bh][d*128+l], 16 chunks
__device__ u16 g_attT[524288];         // 1 MiB   [bh][l*128+d]
__device__ float g_Z[4096];            //         [b*1024+d]

__device__ __forceinline__ float b2f(u16 u) {
  union { unsigned int i; float f; } c;
  c.i = ((unsigned int)u) << 16;
  return c.f;
}
__device__ __forceinline__ u16 f2b(float f) {
  union { float f; unsigned int i; } c;
  c.f = f;
  unsigned int r = c.i + 0x7fffu + ((c.i >> 16) & 1u);
  return (u16)(r >> 16);
}

__device__ __forceinline__ void gload16(const void* g, void* l) {
  __builtin_amdgcn_global_load_lds(
      reinterpret_cast<const __attribute__((address_space(1))) uint32_t*>(
          reinterpret_cast<uintptr_t>(g)),
      reinterpret_cast<__attribute__((address_space(3))) uint32_t*>(
          reinterpret_cast<uintptr_t>(l)),
      16, 0, 0);
}

// Stage 128x32 bf16 tile (row stride `stride` elems) into 8KB LDS [128][32].
// (used by gemm_att — unchanged)
__device__ __forceinline__ void stage128x32(const u16* g, int stride, char* lds,
                                            int wave, int lane) {
  const int r = wave * 32 + (lane >> 2);
  const int cb = (lane & 3) * 16;
  const char* gp = (const char*)g;
  gload16(gp + (size_t)r * stride * 2 + cb, lds + wave * 2048);
  gload16(gp + (size_t)(r + 16) * stride * 2 + cb, lds + wave * 2048 + 1024);
}

// A/B fragment from [128][32] LDS tile: row `row`, k = (lane>>4)*8 .. +7
__device__ __forceinline__ bf16x8 frag_ld(const char* lds, int row, int lane) {
  return *(const bf16x8*)(lds + row * 64 + ((lane >> 4) * 16));
}

// 16 MFMA on one staged 128x32 A/B tile pair (gemm_att).
__device__ __forceinline__ void tile_mfma(const char* As, const char* Bs,
                                          f32x4 (&acc)[4][4], int wm, int wn,
                                          int lane) {
  bf16x8 af[4], bfr[4];
#pragma unroll
  for (int i = 0; i < 4; i++) af[i] = frag_ld(As, wm * 64 + i * 16 + (lane & 15), lane);
#pragma unroll
  for (int j = 0; j < 4; j++) bfr[j] = frag_ld(Bs, wn * 64 + j * 16 + (lane & 15), lane);
#pragma unroll
  for (int i = 0; i < 4; i++)
#pragma unroll
    for (int j = 0; j < 4; j++)
      acc[i][j] = __builtin_amdgcn_mfma_f32_16x16x32_bf16(af[i], bfr[j], acc[i][j], 0, 0, 0);
}

// ---------------- 256^2 8-phase helpers (gemm_kv / gemm_qy ph1) ----------------
// [256][64]-bf16 LDS tile, 128B rows. Chunk-XOR swizzle: 16B-chunk slot s of
// row r holds global chunk (s ^ (r&7)). Stage: linear LDS dest (required by
// global_load_lds) + inverse-swizzled per-lane GLOBAL source. Read: swizzled
// ds_read address. Same involution on both sides (rule #21).
__device__ __forceinline__ void stageA256(char* buf, const u16* gsrc, int h,
                                          int wave, int lane) {
#pragma unroll
  for (int i = 0; i < 2; i++) {
    const int ib = i * 64 + wave * 8;  // idx base (wave-uniform)
    const int rowb = (ib & 63) | ((ib & 64) << 1) | (h << 6);
    const int row = rowb + (lane >> 3);
    const int cc = (lane & 7) ^ (row & 7);  // inverse-swizzled source chunk
    gload16((const char*)gsrc + ((size_t)row * 1024 + cc * 8) * 2,
            buf + rowb * 128);
  }
}
__device__ __forceinline__ void stageB256(char* buf, const u16* gsrc, int h,
                                          int wave, int lane) {
#pragma unroll
  for (int i = 0; i < 2; i++) {
    const int ib = i * 64 + wave * 8;
    const int rowb = (ib & 31) | ((ib & 96) << 1) | (h << 5);
    const int row = rowb + (lane >> 3);
    const int cc = (lane & 7) ^ (row & 7);
    gload16((const char*)gsrc + ((size_t)row * 1024 + cc * 8) * 2,
            buf + rowb * 128);
  }
}
// frag read: row R (includes lane&15), k-step ks: global chunk = ks*4 + q
__device__ __forceinline__ bf16x8 fragS(const char* buf, int R, int ks, int lane) {
  const int q = lane >> 4;
  return *(const bf16x8*)(buf + R * 128 + ((((ks << 2) + q) ^ (R & 7)) << 4));
}

// One K-tile (4 phases) in the R8 schedule: compute (Ab,Bb), stage tile t+1
// into (An,Bn). ST=false on the last tile (no staging; ph1 drains vmcnt(0)).
//  ph1 quad(0,0): ds A-ht0+B-ht0 (12 rd); stage A-ht0+B-ht0 (4 ld); vmcnt(4)
//  ph2 quad(0,1): ds B-ht1 (4 rd)       ; stage B-ht1 (2 ld)      ; no wait
//  ph3 quad(1,1): ds A-ht1 (8 rd)       ; stage A-ht1 (2 ld)      ; vmcnt(4)
//  ph4 quad(1,0): regs only             ; no stage                ; vmcnt(2)
template <bool ST>
__device__ __forceinline__ void tile_r8(char* Ab, char* Bb, char* An, char* Bn,
                                        const u16* Agn, const u16* Bgn,
                                        f32x4 (&acc)[8][4], int wave, int lane,
                                        int wm, int wn) {
  bf16x8 a[4][2], bB[2][2][2];

  // ---- phase 1: quad(0,0) ----
#pragma unroll
  for (int rf = 0; rf < 4; rf++) {
    const int R = wm * 128 + rf * 16 + (lane & 15);
#pragma unroll
    for (int ks = 0; ks < 2; ks++) a[rf][ks] = fragS(Ab, R, ks, lane);
  }
#pragma unroll
  for (int cf = 0; cf < 2; cf++) {
    const int R = wn * 64 + cf * 16 + (lane & 15);
#pragma unroll
    for (int ks = 0; ks < 2; ks++) bB[0][cf][ks] = fragS(Bb, R, ks, lane);
  }
  if constexpr (ST) {
    stageA256(An, Agn, 0, wave, lane);
    stageB256(Bn, Bgn, 0, wave, lane);
    asm volatile("s_waitcnt vmcnt(4)" ::: "memory");
  } else {
    asm volatile("s_waitcnt vmcnt(0)" ::: "memory");
  }
  __builtin_amdgcn_s_barrier();
  asm volatile("s_waitcnt lgkmcnt(0)" ::: "memory");
  __builtin_amdgcn_sched_barrier(0);
  __builtin_amdgcn_s_setprio(1);
#pragma unroll
  for (int rf = 0; rf < 4; rf++)
#pragma unroll
    for (int cf = 0; cf < 2; cf++)
#pragma unroll
      for (int ks = 0; ks < 2; ks++)
        acc[rf][cf] = __builtin_amdgcn_mfma_f32_16x16x32_bf16(
            a[rf][ks], bB[0][cf][ks], acc[rf][cf], 0, 0, 0);
  __builtin_amdgcn_s_setprio(0);
  __builtin_amdgcn_s_barrier();
  __builtin_amdgcn_sched_barrier(0);

  // ---- phase 2: quad(0,1) ----
#pragma unroll
  for (int cf = 0; cf < 2; cf++) {
    const int R = wn * 64 + 32 + cf * 16 + (lane & 15);
#pragma unroll
    for (int ks = 0; ks < 2; ks++) bB[1][cf][ks] = fragS(Bb, R, ks, lane);
  }
  if constexpr (ST) stageB256(Bn, Bgn, 1, wave, lane);
  __builtin_amdgcn_s_barrier();
  asm volatile("s_waitcnt lgkmcnt(0)" ::: "memory");
  __builtin_amdgcn_sched_barrier(0);
  __builtin_amdgcn_s_setprio(1);
#pragma unroll
  for (int rf = 0; rf < 4; rf++)
#pragma unroll
    for (int cf = 0; cf < 2; cf++)
#pragma unroll
      for (int ks = 0; ks < 2; ks++)
        acc[rf][2 + cf] = __builtin_amdgcn_mfma_f32_16x16x32_bf16(
            a[rf][ks], bB[1][cf][ks], acc[rf][2 + cf], 0, 0, 0);
  __builtin_amdgcn_s_setprio(0);
  __builtin_amdgcn_s_barrier();
  __builtin_amdgcn_sched_barrier(0);

  // ---- phase 3: quad(1,1) ----
#pragma unroll
  for (int rf = 0; rf < 4; rf++) {
    const int R = wm * 128 + 64 + rf * 16 + (lane & 15);
#pragma unroll
    for (int ks = 0; ks < 2; ks++) a[rf][ks] = fragS(Ab, R, ks, lane);
  }
  if constexpr (ST) stageA256(An, Agn, 1, wave, lane);
  asm volatile("s_waitcnt vmcnt(4)" ::: "memory");
  __builtin_amdgcn_s_barrier();
  asm volatile("s_waitcnt lgkmcnt(0)" ::: "memory");
  __builtin_amdgcn_sched_barrier(0);
  __builtin_amdgcn_s_setprio(1);
#pragma unroll
  for (int rf = 0; rf < 4; rf++)
#pragma unroll
    for (int cf = 0; cf < 2; cf++)
#pragma unroll
      for (int ks = 0; ks < 2; ks++)
        acc[4 + rf][2 + cf] = __builtin_amdgcn_mfma_f32_16x16x32_bf16(
            a[rf][ks], bB[1][cf][ks], acc[4 + rf][2 + cf], 0, 0, 0);
  __builtin_amdgcn_s_setprio(0);
  __builtin_amdgcn_s_barrier();
  __builtin_amdgcn_sched_barrier(0);

  // ---- phase 4: quad(1,0) — register-only ----
  asm volatile("s_waitcnt vmcnt(2)" ::: "memory");
  __builtin_amdgcn_s_barrier();
  __builtin_amdgcn_s_setprio(1);
#pragma unroll
  for (int rf = 0; rf < 4; rf++)
#pragma unroll
    for (int cf = 0; cf < 2; cf++)
#pragma unroll
      for (int ks = 0; ks < 2; ks++)
        acc[4 + rf][cf] = __builtin_amdgcn_mfma_f32_16x16x32_bf16(
            a[rf][ks], bB[0][cf][ks], acc[4 + rf][cf], 0, 0, 0);
  __builtin_amdgcn_s_setprio(0);
  __builtin_amdgcn_s_barrier();
  __builtin_amdgcn_sched_barrier(0);
}

// ---------------------------- prep: LN (blocks 0..16383) + W transpose (rest)
__global__ __launch_bounds__(256) void prep_kernel(const float* __restrict__ x,
                                                   const float* __restrict__ gamma,
                                                   const float* __restrict__ beta,
                                                   const float* __restrict__ wq,
                                                   const float* __restrict__ wk,
                                                   const float* __restrict__ wv) {
  __shared__ float ls[4], ls2[4];
  __shared__ u16 tile[32][33];
  const int bid = blockIdx.x;
  const int tid = threadIdx.x;
  if (bid < 16384) {
    if (bid < 16) g_Z[bid * 256 + tid] = 0.0f;  // per-launch Z reset
    const int wave = tid >> 6, lane = tid & 63;
    const float* xr = x + (size_t)bid * 1024;
    float4 u = ((const float4*)xr)[tid];
    float v0 = u.x, v1 = u.y, v2 = u.z, v3 = u.w;
    float s = v0 + v1 + v2 + v3;
    float s2 = v0 * v0 + v1 * v1 + v2 * v2 + v3 * v3;
#pragma unroll
    for (int off = 32; off > 0; off >>= 1) {
      s += __shfl_down(s, off);
      s2 += __shfl_down(s2, off);
    }
    if (lane == 0) { ls[wave] = s; ls2[wave] = s2; }
    __syncthreads();
    s = ls[0] + ls[1] + ls[2] + ls[3];
    s2 = ls2[0] + ls2[1] + ls2[2] + ls2[3];
    const float mu = s * (1.0f / 1024.0f);
    const float var = fmaxf(s2 * (1.0f / 1024.0f) - mu * mu, 0.0f);
    const float rstd = rsqrtf(var + 1e-5f);
    float4 g4 = ((const float4*)gamma)[tid];
    float4 be = ((const float4*)beta)[tid];
    ushort4 o;
    o.x = f2b((v0 - mu) * rstd * g4.x + be.x);
    o.y = f2b((v1 - mu) * rstd * g4.y + be.y);
    o.z = f2b((v2 - mu) * rstd * g4.z + be.z);
    o.w = f2b((v3 - mu) * rstd * g4.w + be.w);
    *(ushort4*)(g_xn + (size_t)bid * 1024 + tid * 4) = o;
  } else {
    const int id = bid - 16384;
    const int which = id >> 10;
    const int rem = id & 1023;
    const float* src = (which == 0) ? wq : (which == 1) ? wk : wv;
    u16* dst = g_WT[which];
    const int tx = tid & 31;
    const int ty = tid >> 5;
    const int c0 = (rem & 31) * 32, r0 = (rem >> 5) * 32;
#pragma unroll
    for (int i = 0; i < 4; i++)
      tile[ty + i * 8][tx] = f2b(src[(size_t)(r0 + ty + i * 8) * 1024 + c0 + tx]);
    __syncthreads();
#pragma unroll
    for (int i = 0; i < 4; i++)
      dst[(size_t)(c0 + ty + i * 8) * 1024 + r0 + tx] = tile[tx][ty + i * 8];
  }
}

// --------------------------------------------------------------- K/V GEMM
// 256^2 tile, R8 8-phase schedule. Grid 512 = 64 m-tiles x 8 n-variants
// (4 n0 per z x 2 z). XCD swizzle: c=L&7 -> m-tile = c + 8*(L>>6); the 8
// n-variants of one m-tile are consecutive L on one XCD (share A-slab).
// z=0: ekT[b][d][t] = (m>0.5) ? exp(xn@Wk^T + bk) : 0   (+ fused Z row-sums)
// z=1: vvT[b][l][t] = (xn@Wv^T + bv) * m
__global__ __launch_bounds__(512, 2) void gemm_kv(const float* __restrict__ bk,
                                                  const float* __restrict__ bv,
                                                  const float* __restrict__ mask) {
  __shared__ __align__(16) char smem[131072];
  const int tid = threadIdx.x, wave = tid >> 6, lane = tid & 63;
  const int L = blockIdx.x;
  const int mt = (L & 7) + 8 * (L >> 6);
  const int nt = (L >> 3) & 7;
  const int n0 = (nt & 3) * 256;
  const int z = nt >> 2;
  const int m0 = mt * 256;
  const u16* wt = z ? g_WT[2] : g_WT[1];
  const float* bias = z ? bv : bk;
  u16* outT = z ? g_vvT : g_ekT;
  const int b = m0 >> 12;
  const int t0 = m0 & 4095;
  const int wm = wave >> 2, wn = wave & 3;
  const u16* Ag = g_xn + (size_t)m0 * 1024;
  const u16* Bg = wt + (size_t)n0 * 1024;

  f32x4 zero = {0.f, 0.f, 0.f, 0.f};
  f32x4 acc[8][4];
#pragma unroll
  for (int i = 0; i < 8; i++)
#pragma unroll
    for (int j = 0; j < 4; j++) acc[i][j] = zero;

  // prologue: stage tile 0 fully into buffer 0, full drain (allowed once)
  stageA256(smem, Ag, 0, wave, lane);
  stageB256(smem + 65536, Bg, 0, wave, lane);
  stageA256(smem, Ag, 1, wave, lane);
  stageB256(smem + 65536, Bg, 1, wave, lane);
  asm volatile("s_waitcnt vmcnt(0)" ::: "memory");
  __builtin_amdgcn_s_barrier();

#pragma unroll 1
  for (int t = 0; t < 15; ++t) {
    const int p = t & 1;
    tile_r8<true>(smem + p * 32768, smem + 65536 + p * 32768,
                  smem + (p ^ 1) * 32768, smem + 65536 + (p ^ 1) * 32768,
                  Ag + (t + 1) * 64, Bg + (t + 1) * 64, acc, wave, lane, wm, wn);
  }
  tile_r8<false>(smem + 32768, smem + 65536 + 32768, smem, smem + 65536, Ag, Bg,
                 acc, wave, lane, wm, wn);

  // epilogue: bias + mask/exp, fused zrow, transpose via swizzled LDS, store.
  u16* tT = (u16*)smem;
  float fsum[4] = {0.f, 0.f, 0.f, 0.f};
#pragma unroll
  for (int rf = 0; rf < 8; rf++)
#pragma unroll
    for (int r = 0; r < 4; r++) {
      const int tok = wm * 128 + rf * 16 + (lane >> 4) * 4 + r;
      const float mv = mask[m0 + tok];
#pragma unroll
      for (int cf = 0; cf < 4; cf++) {
        const int feat = wn * 64 + cf * 16 + (lane & 15);
        const float aV = acc[rf][cf][r] + bias[n0 + feat];
        float o;
        if (z)
          o = aV * mv;
        else
          o = (mv > 0.5f) ? __expf(fminf(aV, 30.0f)) : 0.0f;
        const u16 ob = f2b(o);
        tT[feat * 256 + ((((tok >> 3) ^ (feat & 7)) << 3) | (tok & 7))] = ob;
        if (!z) fsum[cf] += b2f(ob);  // sum rounded values == zrow semantics
      }
    }
  if (!z) {
#pragma unroll
    for (int cf = 0; cf < 4; cf++) {
      float s = fsum[cf];
      s += __shfl_xor(s, 16);
      s += __shfl_xor(s, 32);
      if (lane < 16)
        atomicAdd(&g_Z[b * 1024 + n0 + wn * 64 + cf * 16 + lane], s);
    }
  }
  __syncthreads();
  const size_t gbase = (size_t)b * (1024 * 4096) + (size_t)n0 * 4096 + t0;
#pragma unroll
  for (int u = 0; u < 16; u++) {
    const int id = u * 512 + tid;
    const int feat = id >> 5, c = id & 31;
    uint4 val = *(const uint4*)&tT[feat * 256 + ((c ^ (feat & 7)) << 3)];
    *(uint4*)(outT + gbase + (size_t)feat * 4096 + c * 8) = val;
  }
}

// ------------------------------------------------------------- att GEMM
// attp[kc][bh][d][l] = sum_{t in 256-chunk kc} ekT[b][h*128+d][t]*vvT[b][h*128+l][t]
__global__ __launch_bounds__(256) void gemm_att() {
  __shared__ __align__(16) char smem[32768];
  char* A0 = smem;
  char* B0 = smem + 8192;
  char* A1 = smem + 16384;
  char* B1 = smem + 24576;
  const int tid = threadIdx.x, wave = tid >> 6, lane = tid & 63;
  const int kc = blockIdx.x;  // 0..15
  const int bh = blockIdx.y;  // 0..31
  const int b = bh >> 3, h = bh & 7;
  const size_t base = (size_t)b * (1024 * 4096) + (size_t)(h * 128) * 4096;
  const int wm = wave & 1, wn = wave >> 1;
  const u16* Ag = g_ekT + base + kc * 256;
  const u16* Bg = g_vvT + base + kc * 256;

  f32x4 zero = {0.f, 0.f, 0.f, 0.f};
  f32x4 acc[4][4];
#pragma unroll
  for (int i = 0; i < 4; i++)
#pragma unroll
    for (int j = 0; j < 4; j++) acc[i][j] = zero;

  stage128x32(Ag, 4096, A0, wave, lane);
  stage128x32(Bg, 4096, B0, wave, lane);
  __syncthreads();
  for (int kt = 0; kt < 256; kt += 64) {
    stage128x32(Ag + kt + 32, 4096, A1, wave, lane);
    stage128x32(Bg + kt + 32, 4096, B1, wave, lane);
    tile_mfma(A0, B0, acc, wm, wn, lane);
    __syncthreads();
    if (kt + 64 < 256) {
      stage128x32(Ag + kt + 64, 4096, A0, wave, lane);
      stage128x32(Bg + kt + 64, 4096, B0, wave, lane);
    }
    tile_mfma(A1, B1, acc, wm, wn, lane);
    __syncthreads();
  }

  float* op = g_attp + ((size_t)(kc * 32 + bh)) * 16384;
#pragma unroll
  for (int i = 0; i < 4; i++)
#pragma unroll
    for (int r = 0; r < 4; r++) {
      const int row = wm * 64 + i * 16 + (lane >> 4) * 4 + r;
#pragma unroll
      for (int j = 0; j < 4; j++) {
        const int col = wn * 64 + j * 16 + (lane & 15);
        op[row * 128 + col] = acc[i][j][r];
      }
    }
}

// ------------------------------------- reduce partials, /Z, store attT[bh][l][d]
__global__ __launch_bounds__(256) void attnorm_kernel() {
  const int bh = blockIdx.x;
  const int b = bh >> 3, h = bh & 7;
  const int tid = threadIdx.x;
  __shared__ float Zl[128];
  if (tid < 128) Zl[tid] = fmaxf(g_Z[b * 1024 + h * 128 + tid], 1e-30f);
  __syncthreads();
  const int i0 = blockIdx.y * 2048;
  for (int i = i0 + tid; i < i0 + 2048; i += 256) {
    const int d = i >> 7, l = i & 127;
    float s = 0.f;
#pragma unroll
    for (int c = 0; c < 16; c++) s += g_attp[((size_t)(c * 32 + bh)) * 16384 + i];
    g_attT[(size_t)bh * 16384 + l * 128 + d] = f2b(s / Zl[d]);
  }
}

// ---------------------------------------------------------- fused q + y
// 256^2 8-phase phase-1 over the FULL feature dim (tile = 2 heads). Grid 256
// (64 m-tiles x 4 n-tiles) = exactly one round of 256 CUs. XCD swizzle:
// c=L&7, g=L>>3; mt = c + 8*(g>>2); ntile = g&3 (4 n-variants per m on 1 XCD).
// ph1: q = xn @ WqT (K=1024). Epilogue-1: exp(q+bq) -> swizzled qs[256][256]
// in LDS + per-head row sums (zq4). ph2: y = P @ attT (K=128, 2 heads), A
// from qs (chunk includes hl<<4 head offset — R11 fix), B straight from
// global attT (64KB/block, L2-hot). Epilogue-2: out = x + y/zq.
__global__ __launch_bounds__(512, 2) void gemm_qy(const float* __restrict__ bq,
                                                  const float* __restrict__ x,
                                                  float* __restrict__ out) {
  __shared__ __align__(16) char smem[131072];
  __shared__ float zq4[4][256];
  const int tid = threadIdx.x, wave = tid >> 6, lane = tid & 63;
  const int L = blockIdx.x;
  const int g = L >> 3;
  const int mt = (L & 7) + 8 * (g >> 2);
  const int n0 = (g & 3) * 256;
  const int m0 = mt * 256;
  const int b = m0 >> 12;
  const int wm = wave >> 2, wn = wave & 3;
  const u16* Ag = g_xn + (size_t)m0 * 1024;
  const u16* Bg = g_WT[0] + (size_t)n0 * 1024;

  f32x4 zero = {0.f, 0.f, 0.f, 0.f};
  f32x4 acc[8][4];
#pragma unroll
  for (int i = 0; i < 8; i++)
#pragma unroll
    for (int j = 0; j < 4; j++) acc[i][j] = zero;

  // prologue
  stageA256(smem, Ag, 0, wave, lane);
  stageB256(smem + 65536, Bg, 0, wave, lane);
  stageA256(smem, Ag, 1, wave, lane);
  stageB256(smem + 65536, Bg, 1, wave, lane);
  asm volatile("s_waitcnt vmcnt(0)" ::: "memory");
  __builtin_amdgcn_s_barrier();

#pragma unroll 1
  for (int t = 0; t < 15; ++t) {
    const int p = t & 1;
    tile_r8<true>(smem + p * 32768, smem + 65536 + p * 32768,
                  smem + (p ^ 1) * 32768, smem + 65536 + (p ^ 1) * 32768,
                  Ag + (t + 1) * 64, Bg + (t + 1) * 64, acc, wave, lane, wm, wn);
  }
  tile_r8<false>(smem + 32768, smem + 65536 + 32768, smem, smem + 65536, Ag, Bg,
                 acc, wave, lane, wm, wn);

  // epilogue-1: e = exp(q + bq) (clamped); write swizzled qs[tok][feat] into
  // the freed smem (slot = (feat>>3) ^ (tok&31), bijective per row); per-head
  // row-sums into zq4[wn][tok] (each wave's 64 cols lie in ONE head).
  u16* qs = (u16*)smem;
#pragma unroll
  for (int rf = 0; rf < 8; rf++)
#pragma unroll
    for (int r = 0; r < 4; r++) {
      const int tok = wm * 128 + rf * 16 + (lane >> 4) * 4 + r;
      float rs = 0.f;
#pragma unroll
      for (int cf = 0; cf < 4; cf++) {
        const int f = wn * 64 + cf * 16 + (lane & 15);
        const float e = __expf(fminf(acc[rf][cf][r] + bq[n0 + f], 30.0f));
        qs[tok * 256 + ((((f >> 3) ^ (tok & 31)) << 3) | (f & 7))] = f2b(e);
        rs += e;
      }
      rs += __shfl_xor(rs, 1);
      rs += __shfl_xor(rs, 2);
      rs += __shfl_xor(rs, 4);
      rs += __shfl_xor(rs, 8);
      if ((lane & 15) == 0) zq4[wn][tok] = rs;
    }
  __syncthreads();

  // phase 2: y[tok, col] = sum_d P[tok, hl*128+d] * attT[bhh][l*128 + d].
  // A-frags from swizzled qs (chunk = hl*16 + ks*4 + q — head offset!);
  // B-frags straight from global attT (L2-hot).
  const int hl = wn >> 1;                      // head within the 2-head pair
  const int bhh = b * 8 + (n0 >> 7) + hl;
  const u16* attb = g_attT + ((size_t)bhh << 14);
  f32x4 acc2[8][4];
#pragma unroll
  for (int i = 0; i < 8; i++)
#pragma unroll
    for (int j = 0; j < 4; j++) acc2[i][j] = zero;

#pragma unroll
  for (int ks = 0; ks < 4; ks++) {
    bf16x8 bf[4];
#pragma unroll
    for (int cf = 0; cf < 4; cf++) {
      const int l = (wn & 1) * 64 + cf * 16 + (lane & 15);  // output col (in head)
      bf[cf] = *(const bf16x8*)(attb + l * 128 + ks * 32 + (lane >> 4) * 8);
    }
    bf16x8 af[8];
#pragma unroll
    for (int rf = 0; rf < 8; rf++) {
      const int tok = wm * 128 + rf * 16 + (lane & 15);
      af[rf] = *(const bf16x8*)&qs[tok * 256 +
          ((((hl << 4) + (ks << 2) + (lane >> 4)) ^ (tok & 31)) << 3)];
    }
#pragma unroll
    for (int rf = 0; rf < 8; rf++)
#pragma unroll
      for (int cf = 0; cf < 4; cf++)
        acc2[rf][cf] = __builtin_amdgcn_mfma_f32_16x16x32_bf16(
            af[rf], bf[cf], acc2[rf][cf], 0, 0, 0);
  }

  // epilogue-2: out = x + y / zq  (fp32)
#pragma unroll
  for (int rf = 0; rf < 8; rf++)
#pragma unroll
    for (int r = 0; r < 4; r++) {
      const int tok = wm * 128 + rf * 16 + (lane >> 4) * 4 + r;
      const float zq =
          fmaxf(zq4[hl * 2][tok] + zq4[hl * 2 + 1][tok], 1e-30f);
      const size_t n = (size_t)(m0 + tok);
#pragma unroll
      for (int cf = 0; cf < 4; cf++) {
        const int f = wn * 64 + cf * 16 + (lane & 15);
        const size_t idx = n * 1024 + n0 + f;
        out[idx] = x[idx] + acc2[rf][cf][r] / zq;
      }
    }
}

// ----------------------------------------------------------------- launch
extern "C" void kernel_launch(void* const* d_in, const int* in_sizes, int n_in,
                              void* d_out, int out_size, void* d_ws, size_t ws_size,
                              hipStream_t stream) {
  const float* x = (const float*)d_in[0];
  const float* mask = (const float*)d_in[1];
  const float* Wq = (const float*)d_in[2];
  const float* bq = (const float*)d_in[3];
  const float* Wk = (const float*)d_in[4];
  const float* bk = (const float*)d_in[5];
  const float* Wv = (const float*)d_in[6];
  const float* bv = (const float*)d_in[7];
  const float* gamma = (const float*)d_in[8];
  const float* beta = (const float*)d_in[9];
  float* out = (float*)d_out;
  (void)d_ws; (void)ws_size;

  prep_kernel<<<dim3(16384 + 3072), 256, 0, stream>>>(x, gamma, beta, Wq, Wk, Wv);
  gemm_kv<<<dim3(512), 512, 0, stream>>>(bk, bv, mask);
  gemm_att<<<dim3(16, 32), 256, 0, stream>>>();
  attnorm_kernel<<<dim3(32, 8), 256, 0, stream>>>();
  gemm_qy<<<dim3(256), 512, 0, stream>>>(bq, x, out);
}

// Round 7
// 329.606 us; speedup vs baseline: 1.0219x; 1.0061x over previous
//
#include <hip/hip_runtime.h>
#include <stdint.h>

// EfficientSelfAttention on MI355X (gfx950). External I/O FP32; internals bf16
// MFMA. B=4, T=4096, D=1024, H=8, Dh=128. Scratch in __device__ globals.
// R13: R12 minus the buggy prep change (2-rows/block LN only covered half of
//      each row — reverted to the proven 1-row/block form). Keeps:
//  - gemm_att: 16 -> 8 K-chunks (256 blocks, K=512) => attp halves to 16MB;
//    attnorm reads 8 chunks (half traffic). Total k-iterations unchanged.
//  - gemm_qy: ALL phase-2 attT B-fragments (16 x bf16x8 = 64 VGPR) loaded
//    right after ph1, before epilogue-1 -> L2 latency hides under exp/shuffle
//    VALU. LDS (132KB) already caps at 1 block/CU so VGPR headroom is free.
//  - gemm_kv unchanged (R8 schedule, stable 93us / 30% MfmaUtil).

typedef unsigned short u16;
typedef __attribute__((ext_vector_type(8))) short bf16x8;
typedef __attribute__((ext_vector_type(4))) float f32x4;

// ------------------------------------------------------- device workspace
__device__ u16 g_WT[3][1024 * 1024];   // 6 MiB: WqT, WkT, WvT (bf16)
__device__ u16 g_xn[16777216];         // 32 MiB
__device__ u16 g_ekT[16777216];        // 32 MiB  [b][d][t]
__device__ u16 g_vvT[16777216];        // 32 MiB  [b][l][t]
__device__ float g_attp[8388608];      // 32 MiB  [kc*32+bh][d*128+l], 8 chunks used
__device__ u16 g_attT[524288];         // 1 MiB   [bh][l*128+d]
__device__ float g_Z[4096];            //         [b*1024+d]

__device__ __forceinline__ float b2f(u16 u) {
  union { unsigned int i; float f; } c;
  c.i = ((unsigned int)u) << 16;
  return c.f;
}
__device__ __forceinline__ u16 f2b(float f) {
  union { float f; unsigned int i; } c;
  c.f = f;
  unsigned int r = c.i + 0x7fffu + ((c.i >> 16) & 1u);
  return (u16)(r >> 16);
}

__device__ __forceinline__ void gload16(const void* g, void* l) {
  __builtin_amdgcn_global_load_lds(
      reinterpret_cast<const __attribute__((address_space(1))) uint32_t*>(
          reinterpret_cast<uintptr_t>(g)),
      reinterpret_cast<__attribute__((address_space(3))) uint32_t*>(
          reinterpret_cast<uintptr_t>(l)),
      16, 0, 0);
}

// Stage 128x32 bf16 tile (row stride `stride` elems) into 8KB LDS [128][32].
// (used by gemm_att)
__device__ __forceinline__ void stage128x32(const u16* g, int stride, char* lds,
                                            int wave, int lane) {
  const int r = wave * 32 + (lane >> 2);
  const int cb = (lane & 3) * 16;
  const char* gp = (const char*)g;
  gload16(gp + (size_t)r * stride * 2 + cb, lds + wave * 2048);
  gload16(gp + (size_t)(r + 16) * stride * 2 + cb, lds + wave * 2048 + 1024);
}

// A/B fragment from [128][32] LDS tile: row `row`, k = (lane>>4)*8 .. +7
__device__ __forceinline__ bf16x8 frag_ld(const char* lds, int row, int lane) {
  return *(const bf16x8*)(lds + row * 64 + ((lane >> 4) * 16));
}

// 16 MFMA on one staged 128x32 A/B tile pair (gemm_att).
__device__ __forceinline__ void tile_mfma(const char* As, const char* Bs,
                                          f32x4 (&acc)[4][4], int wm, int wn,
                                          int lane) {
  bf16x8 af[4], bfr[4];
#pragma unroll
  for (int i = 0; i < 4; i++) af[i] = frag_ld(As, wm * 64 + i * 16 + (lane & 15), lane);
#pragma unroll
  for (int j = 0; j < 4; j++) bfr[j] = frag_ld(Bs, wn * 64 + j * 16 + (lane & 15), lane);
#pragma unroll
  for (int i = 0; i < 4; i++)
#pragma unroll
    for (int j = 0; j < 4; j++)
      acc[i][j] = __builtin_amdgcn_mfma_f32_16x16x32_bf16(af[i], bfr[j], acc[i][j], 0, 0, 0);
}

// ---------------- 256^2 8-phase helpers (gemm_kv / gemm_qy ph1) ----------------
// [256][64]-bf16 LDS tile, 128B rows. Chunk-XOR swizzle: 16B-chunk slot s of
// row r holds global chunk (s ^ (r&7)). Stage: linear LDS dest (required by
// global_load_lds) + inverse-swizzled per-lane GLOBAL source. Read: swizzled
// ds_read address. Same involution on both sides (rule #21).
__device__ __forceinline__ void stageA256(char* buf, const u16* gsrc, int h,
                                          int wave, int lane) {
#pragma unroll
  for (int i = 0; i < 2; i++) {
    const int ib = i * 64 + wave * 8;  // idx base (wave-uniform)
    const int rowb = (ib & 63) | ((ib & 64) << 1) | (h << 6);
    const int row = rowb + (lane >> 3);
    const int cc = (lane & 7) ^ (row & 7);  // inverse-swizzled source chunk
    gload16((const char*)gsrc + ((size_t)row * 1024 + cc * 8) * 2,
            buf + rowb * 128);
  }
}
__device__ __forceinline__ void stageB256(char* buf, const u16* gsrc, int h,
                                          int wave, int lane) {
#pragma unroll
  for (int i = 0; i < 2; i++) {
    const int ib = i * 64 + wave * 8;
    const int rowb = (ib & 31) | ((ib & 96) << 1) | (h << 5);
    const int row = rowb + (lane >> 3);
    const int cc = (lane & 7) ^ (row & 7);
    gload16((const char*)gsrc + ((size_t)row * 1024 + cc * 8) * 2,
            buf + rowb * 128);
  }
}
// frag read: row R (includes lane&15), k-step ks: global chunk = ks*4 + q
__device__ __forceinline__ bf16x8 fragS(const char* buf, int R, int ks, int lane) {
  const int q = lane >> 4;
  return *(const bf16x8*)(buf + R * 128 + ((((ks << 2) + q) ^ (R & 7)) << 4));
}

// One K-tile (4 phases) in the R8 schedule: compute (Ab,Bb), stage tile t+1
// into (An,Bn). ST=false on the last tile (no staging; ph1 drains vmcnt(0)).
//  ph1 quad(0,0): ds A-ht0+B-ht0 (12 rd); stage A-ht0+B-ht0 (4 ld); vmcnt(4)
//  ph2 quad(0,1): ds B-ht1 (4 rd)       ; stage B-ht1 (2 ld)      ; no wait
//  ph3 quad(1,1): ds A-ht1 (8 rd)       ; stage A-ht1 (2 ld)      ; vmcnt(4)
//  ph4 quad(1,0): regs only             ; no stage                ; vmcnt(2)
template <bool ST>
__device__ __forceinline__ void tile_r8(char* Ab, char* Bb, char* An, char* Bn,
                                        const u16* Agn, const u16* Bgn,
                                        f32x4 (&acc)[8][4], int wave, int lane,
                                        int wm, int wn) {
  bf16x8 a[4][2], bB[2][2][2];

  // ---- phase 1: quad(0,0) ----
#pragma unroll
  for (int rf = 0; rf < 4; rf++) {
    const int R = wm * 128 + rf * 16 + (lane & 15);
#pragma unroll
    for (int ks = 0; ks < 2; ks++) a[rf][ks] = fragS(Ab, R, ks, lane);
  }
#pragma unroll
  for (int cf = 0; cf < 2; cf++) {
    const int R = wn * 64 + cf * 16 + (lane & 15);
#pragma unroll
    for (int ks = 0; ks < 2; ks++) bB[0][cf][ks] = fragS(Bb, R, ks, lane);
  }
  if constexpr (ST) {
    stageA256(An, Agn, 0, wave, lane);
    stageB256(Bn, Bgn, 0, wave, lane);
    asm volatile("s_waitcnt vmcnt(4)" ::: "memory");
  } else {
    asm volatile("s_waitcnt vmcnt(0)" ::: "memory");
  }
  __builtin_amdgcn_s_barrier();
  asm volatile("s_waitcnt lgkmcnt(0)" ::: "memory");
  __builtin_amdgcn_sched_barrier(0);
  __builtin_amdgcn_s_setprio(1);
#pragma unroll
  for (int rf = 0; rf < 4; rf++)
#pragma unroll
    for (int cf = 0; cf < 2; cf++)
#pragma unroll
      for (int ks = 0; ks < 2; ks++)
        acc[rf][cf] = __builtin_amdgcn_mfma_f32_16x16x32_bf16(
            a[rf][ks], bB[0][cf][ks], acc[rf][cf], 0, 0, 0);
  __builtin_amdgcn_s_setprio(0);
  __builtin_amdgcn_s_barrier();
  __builtin_amdgcn_sched_barrier(0);

  // ---- phase 2: quad(0,1) ----
#pragma unroll
  for (int cf = 0; cf < 2; cf++) {
    const int R = wn * 64 + 32 + cf * 16 + (lane & 15);
#pragma unroll
    for (int ks = 0; ks < 2; ks++) bB[1][cf][ks] = fragS(Bb, R, ks, lane);
  }
  if constexpr (ST) stageB256(Bn, Bgn, 1, wave, lane);
  __builtin_amdgcn_s_barrier();
  asm volatile("s_waitcnt lgkmcnt(0)" ::: "memory");
  __builtin_amdgcn_sched_barrier(0);
  __builtin_amdgcn_s_setprio(1);
#pragma unroll
  for (int rf = 0; rf < 4; rf++)
#pragma unroll
    for (int cf = 0; cf < 2; cf++)
#pragma unroll
      for (int ks = 0; ks < 2; ks++)
        acc[rf][2 + cf] = __builtin_amdgcn_mfma_f32_16x16x32_bf16(
            a[rf][ks], bB[1][cf][ks], acc[rf][2 + cf], 0, 0, 0);
  __builtin_amdgcn_s_setprio(0);
  __builtin_amdgcn_s_barrier();
  __builtin_amdgcn_sched_barrier(0);

  // ---- phase 3: quad(1,1) ----
#pragma unroll
  for (int rf = 0; rf < 4; rf++) {
    const int R = wm * 128 + 64 + rf * 16 + (lane & 15);
#pragma unroll
    for (int ks = 0; ks < 2; ks++) a[rf][ks] = fragS(Ab, R, ks, lane);
  }
  if constexpr (ST) stageA256(An, Agn, 1, wave, lane);
  asm volatile("s_waitcnt vmcnt(4)" ::: "memory");
  __builtin_amdgcn_s_barrier();
  asm volatile("s_waitcnt lgkmcnt(0)" ::: "memory");
  __builtin_amdgcn_sched_barrier(0);
  __builtin_amdgcn_s_setprio(1);
#pragma unroll
  for (int rf = 0; rf < 4; rf++)
#pragma unroll
    for (int cf = 0; cf < 2; cf++)
#pragma unroll
      for (int ks = 0; ks < 2; ks++)
        acc[4 + rf][2 + cf] = __builtin_amdgcn_mfma_f32_16x16x32_bf16(
            a[rf][ks], bB[1][cf][ks], acc[4 + rf][2 + cf], 0, 0, 0);
  __builtin_amdgcn_s_setprio(0);
  __builtin_amdgcn_s_barrier();
  __builtin_amdgcn_sched_barrier(0);

  // ---- phase 4: quad(1,0) — register-only ----
  asm volatile("s_waitcnt vmcnt(2)" ::: "memory");
  __builtin_amdgcn_s_barrier();
  __builtin_amdgcn_s_setprio(1);
#pragma unroll
  for (int rf = 0; rf < 4; rf++)
#pragma unroll
    for (int cf = 0; cf < 2; cf++)
#pragma unroll
      for (int ks = 0; ks < 2; ks++)
        acc[4 + rf][cf] = __builtin_amdgcn_mfma_f32_16x16x32_bf16(
            a[rf][ks], bB[0][cf][ks], acc[4 + rf][cf], 0, 0, 0);
  __builtin_amdgcn_s_setprio(0);
  __builtin_amdgcn_s_barrier();
  __builtin_amdgcn_sched_barrier(0);
}

// ---------------------------- prep: LN (blocks 0..16383) + W transpose (rest)
__global__ __launch_bounds__(256) void prep_kernel(const float* __restrict__ x,
                                                   const float* __restrict__ gamma,
                                                   const float* __restrict__ beta,
                                                   const float* __restrict__ wq,
                                                   const float* __restrict__ wk,
                                                   const float* __restrict__ wv) {
  __shared__ float ls[4], ls2[4];
  __shared__ u16 tile[32][33];
  const int bid = blockIdx.x;
  const int tid = threadIdx.x;
  if (bid < 16384) {
    if (bid < 16) g_Z[bid * 256 + tid] = 0.0f;  // per-launch Z reset
    const int wave = tid >> 6, lane = tid & 63;
    const float* xr = x + (size_t)bid * 1024;
    float4 u = ((const float4*)xr)[tid];
    float v0 = u.x, v1 = u.y, v2 = u.z, v3 = u.w;
    float s = v0 + v1 + v2 + v3;
    float s2 = v0 * v0 + v1 * v1 + v2 * v2 + v3 * v3;
#pragma unroll
    for (int off = 32; off > 0; off >>= 1) {
      s += __shfl_down(s, off);
      s2 += __shfl_down(s2, off);
    }
    if (lane == 0) { ls[wave] = s; ls2[wave] = s2; }
    __syncthreads();
    s = ls[0] + ls[1] + ls[2] + ls[3];
    s2 = ls2[0] + ls2[1] + ls2[2] + ls2[3];
    const float mu = s * (1.0f / 1024.0f);
    const float var = fmaxf(s2 * (1.0f / 1024.0f) - mu * mu, 0.0f);
    const float rstd = rsqrtf(var + 1e-5f);
    float4 g4 = ((const float4*)gamma)[tid];
    float4 be = ((const float4*)beta)[tid];
    ushort4 o;
    o.x = f2b((v0 - mu) * rstd * g4.x + be.x);
    o.y = f2b((v1 - mu) * rstd * g4.y + be.y);
    o.z = f2b((v2 - mu) * rstd * g4.z + be.z);
    o.w = f2b((v3 - mu) * rstd * g4.w + be.w);
    *(ushort4*)(g_xn + (size_t)bid * 1024 + tid * 4) = o;
  } else {
    const int id = bid - 16384;
    const int which = id >> 10;
    const int rem = id & 1023;
    const float* src = (which == 0) ? wq : (which == 1) ? wk : wv;
    u16* dst = g_WT[which];
    const int tx = tid & 31;
    const int ty = tid >> 5;
    const int c0 = (rem & 31) * 32, r0 = (rem >> 5) * 32;
#pragma unroll
    for (int i = 0; i < 4; i++)
      tile[ty + i * 8][tx] = f2b(src[(size_t)(r0 + ty + i * 8) * 1024 + c0 + tx]);
    __syncthreads();
#pragma unroll
    for (int i = 0; i < 4; i++)
      dst[(size_t)(c0 + ty + i * 8) * 1024 + r0 + tx] = tile[tx][ty + i * 8];
  }
}

// --------------------------------------------------------------- K/V GEMM
// 256^2 tile, R8 8-phase schedule. Grid 512 = 64 m-tiles x 8 n-variants
// (4 n0 per z x 2 z). XCD swizzle: c=L&7 -> m-tile = c + 8*(L>>6); the 8
// n-variants of one m-tile are consecutive L on one XCD (share A-slab).
// z=0: ekT[b][d][t] = (m>0.5) ? exp(xn@Wk^T + bk) : 0   (+ fused Z row-sums)
// z=1: vvT[b][l][t] = (xn@Wv^T + bv) * m
__global__ __launch_bounds__(512, 2) void gemm_kv(const float* __restrict__ bk,
                                                  const float* __restrict__ bv,
                                                  const float* __restrict__ mask) {
  __shared__ __align__(16) char smem[131072];
  const int tid = threadIdx.x, wave = tid >> 6, lane = tid & 63;
  const int L = blockIdx.x;
  const int mt = (L & 7) + 8 * (L >> 6);
  const int nt = (L >> 3) & 7;
  const int n0 = (nt & 3) * 256;
  const int z = nt >> 2;
  const int m0 = mt * 256;
  const u16* wt = z ? g_WT[2] : g_WT[1];
  const float* bias = z ? bv : bk;
  u16* outT = z ? g_vvT : g_ekT;
  const int b = m0 >> 12;
  const int t0 = m0 & 4095;
  const int wm = wave >> 2, wn = wave & 3;
  const u16* Ag = g_xn + (size_t)m0 * 1024;
  const u16* Bg = wt + (size_t)n0 * 1024;

  f32x4 zero = {0.f, 0.f, 0.f, 0.f};
  f32x4 acc[8][4];
#pragma unroll
  for (int i = 0; i < 8; i++)
#pragma unroll
    for (int j = 0; j < 4; j++) acc[i][j] = zero;

  // prologue: stage tile 0 fully into buffer 0, full drain (allowed once)
  stageA256(smem, Ag, 0, wave, lane);
  stageB256(smem + 65536, Bg, 0, wave, lane);
  stageA256(smem, Ag, 1, wave, lane);
  stageB256(smem + 65536, Bg, 1, wave, lane);
  asm volatile("s_waitcnt vmcnt(0)" ::: "memory");
  __builtin_amdgcn_s_barrier();

#pragma unroll 1
  for (int t = 0; t < 15; ++t) {
    const int p = t & 1;
    tile_r8<true>(smem + p * 32768, smem + 65536 + p * 32768,
                  smem + (p ^ 1) * 32768, smem + 65536 + (p ^ 1) * 32768,
                  Ag + (t + 1) * 64, Bg + (t + 1) * 64, acc, wave, lane, wm, wn);
  }
  tile_r8<false>(smem + 32768, smem + 65536 + 32768, smem, smem + 65536, Ag, Bg,
                 acc, wave, lane, wm, wn);

  // epilogue: bias + mask/exp, fused zrow, transpose via swizzled LDS, store.
  u16* tT = (u16*)smem;
  float fsum[4] = {0.f, 0.f, 0.f, 0.f};
#pragma unroll
  for (int rf = 0; rf < 8; rf++)
#pragma unroll
    for (int r = 0; r < 4; r++) {
      const int tok = wm * 128 + rf * 16 + (lane >> 4) * 4 + r;
      const float mv = mask[m0 + tok];
#pragma unroll
      for (int cf = 0; cf < 4; cf++) {
        const int feat = wn * 64 + cf * 16 + (lane & 15);
        const float aV = acc[rf][cf][r] + bias[n0 + feat];
        float o;
        if (z)
          o = aV * mv;
        else
          o = (mv > 0.5f) ? __expf(fminf(aV, 30.0f)) : 0.0f;
        const u16 ob = f2b(o);
        tT[feat * 256 + ((((tok >> 3) ^ (feat & 7)) << 3) | (tok & 7))] = ob;
        if (!z) fsum[cf] += b2f(ob);  // sum rounded values == zrow semantics
      }
    }
  if (!z) {
#pragma unroll
    for (int cf = 0; cf < 4; cf++) {
      float s = fsum[cf];
      s += __shfl_xor(s, 16);
      s += __shfl_xor(s, 32);
      if (lane < 16)
        atomicAdd(&g_Z[b * 1024 + n0 + wn * 64 + cf * 16 + lane], s);
    }
  }
  __syncthreads();
  const size_t gbase = (size_t)b * (1024 * 4096) + (size_t)n0 * 4096 + t0;
#pragma unroll
  for (int u = 0; u < 16; u++) {
    const int id = u * 512 + tid;
    const int feat = id >> 5, c = id & 31;
    uint4 val = *(const uint4*)&tT[feat * 256 + ((c ^ (feat & 7)) << 3)];
    *(uint4*)(outT + gbase + (size_t)feat * 4096 + c * 8) = val;
  }
}

// ------------------------------------------------------------- att GEMM
// 8 chunks of K=512: attp[kc][bh][d][l] = sum_{t in 512-chunk kc}
// ekT[b][h*128+d][t] * vvT[b][h*128+l][t].  Grid (8, 32) = 256 blocks.
__global__ __launch_bounds__(256) void gemm_att() {
  __shared__ __align__(16) char smem[32768];
  char* A0 = smem;
  char* B0 = smem + 8192;
  char* A1 = smem + 16384;
  char* B1 = smem + 24576;
  const int tid = threadIdx.x, wave = tid >> 6, lane = tid & 63;
  const int kc = blockIdx.x;  // 0..7
  const int bh = blockIdx.y;  // 0..31
  const int b = bh >> 3, h = bh & 7;
  const size_t base = (size_t)b * (1024 * 4096) + (size_t)(h * 128) * 4096;
  const int wm = wave & 1, wn = wave >> 1;
  const u16* Ag = g_ekT + base + kc * 512;
  const u16* Bg = g_vvT + base + kc * 512;

  f32x4 zero = {0.f, 0.f, 0.f, 0.f};
  f32x4 acc[4][4];
#pragma unroll
  for (int i = 0; i < 4; i++)
#pragma unroll
    for (int j = 0; j < 4; j++) acc[i][j] = zero;

  stage128x32(Ag, 4096, A0, wave, lane);
  stage128x32(Bg, 4096, B0, wave, lane);
  __syncthreads();
  for (int kt = 0; kt < 512; kt += 64) {
    stage128x32(Ag + kt + 32, 4096, A1, wave, lane);
    stage128x32(Bg + kt + 32, 4096, B1, wave, lane);
    tile_mfma(A0, B0, acc, wm, wn, lane);
    __syncthreads();
    if (kt + 64 < 512) {
      stage128x32(Ag + kt + 64, 4096, A0, wave, lane);
      stage128x32(Bg + kt + 64, 4096, B0, wave, lane);
    }
    tile_mfma(A1, B1, acc, wm, wn, lane);
    __syncthreads();
  }

  float* op = g_attp + ((size_t)(kc * 32 + bh)) * 16384;
#pragma unroll
  for (int i = 0; i < 4; i++)
#pragma unroll
    for (int r = 0; r < 4; r++) {
      const int row = wm * 64 + i * 16 + (lane >> 4) * 4 + r;
#pragma unroll
      for (int j = 0; j < 4; j++) {
        const int col = wn * 64 + j * 16 + (lane & 15);
        op[row * 128 + col] = acc[i][j][r];
      }
    }
}

// ------------------------------------- reduce partials, /Z, store attT[bh][l][d]
__global__ __launch_bounds__(256) void attnorm_kernel() {
  const int bh = blockIdx.x;
  const int b = bh >> 3, h = bh & 7;
  const int tid = threadIdx.x;
  __shared__ float Zl[128];
  if (tid < 128) Zl[tid] = fmaxf(g_Z[b * 1024 + h * 128 + tid], 1e-30f);
  __syncthreads();
  const int i0 = blockIdx.y * 2048;
  for (int i = i0 + tid; i < i0 + 2048; i += 256) {
    const int d = i >> 7, l = i & 127;
    float s = 0.f;
#pragma unroll
    for (int c = 0; c < 8; c++) s += g_attp[((size_t)(c * 32 + bh)) * 16384 + i];
    g_attT[(size_t)bh * 16384 + l * 128 + d] = f2b(s / Zl[d]);
  }
}

// ---------------------------------------------------------- fused q + y
// 256^2 8-phase phase-1 over the FULL feature dim (tile = 2 heads). Grid 256
// (64 m-tiles x 4 n-tiles) = exactly one round of 256 CUs. XCD swizzle:
// c=L&7, g=L>>3; mt = c + 8*(g>>2); ntile = g&3 (4 n-variants per m on 1 XCD).
// ph1: q = xn @ WqT (K=1024). Then ALL ph2 attT B-frags are loaded (64 VGPR)
// so their latency hides under epilogue-1's exp/shuffle VALU. Epilogue-1:
// exp(q+bq) -> swizzled qs[256][256] in LDS + per-head row sums (zq4).
// ph2: y = P @ attT (K=128, 2 heads), A from qs (chunk includes hl<<4 head
// offset), B from the prefetched regs. Epilogue-2: out = x + y/zq.
__global__ __launch_bounds__(512, 2) void gemm_qy(const float* __restrict__ bq,
                                                  const float* __restrict__ x,
                                                  float* __restrict__ out) {
  __shared__ __align__(16) char smem[131072];
  __shared__ float zq4[4][256];
  const int tid = threadIdx.x, wave = tid >> 6, lane = tid & 63;
  const int L = blockIdx.x;
  const int g = L >> 3;
  const int mt = (L & 7) + 8 * (g >> 2);
  const int n0 = (g & 3) * 256;
  const int m0 = mt * 256;
  const int b = m0 >> 12;
  const int wm = wave >> 2, wn = wave & 3;
  const u16* Ag = g_xn + (size_t)m0 * 1024;
  const u16* Bg = g_WT[0] + (size_t)n0 * 1024;

  f32x4 zero = {0.f, 0.f, 0.f, 0.f};
  f32x4 acc[8][4];
#pragma unroll
  for (int i = 0; i < 8; i++)
#pragma unroll
    for (int j = 0; j < 4; j++) acc[i][j] = zero;

  // prologue
  stageA256(smem, Ag, 0, wave, lane);
  stageB256(smem + 65536, Bg, 0, wave, lane);
  stageA256(smem, Ag, 1, wave, lane);
  stageB256(smem + 65536, Bg, 1, wave, lane);
  asm volatile("s_waitcnt vmcnt(0)" ::: "memory");
  __builtin_amdgcn_s_barrier();

#pragma unroll 1
  for (int t = 0; t < 15; ++t) {
    const int p = t & 1;
    tile_r8<true>(smem + p * 32768, smem + 65536 + p * 32768,
                  smem + (p ^ 1) * 32768, smem + 65536 + (p ^ 1) * 32768,
                  Ag + (t + 1) * 64, Bg + (t + 1) * 64, acc, wave, lane, wm, wn);
  }
  tile_r8<false>(smem + 32768, smem + 65536 + 32768, smem, smem + 65536, Ag, Bg,
                 acc, wave, lane, wm, wn);

  // ---- R12: prefetch ALL ph2 B-fragments from global attT now; their L2
  // latency hides under epilogue-1's exp/shuffle VALU work (no LDS needed).
  const int hl = wn >> 1;                      // head within the 2-head pair
  const int bhh = b * 8 + (n0 >> 7) + hl;
  const u16* attb = g_attT + ((size_t)bhh << 14);
  bf16x8 bpre[4][4];
#pragma unroll
  for (int ks = 0; ks < 4; ks++)
#pragma unroll
    for (int cf = 0; cf < 4; cf++) {
      const int l = (wn & 1) * 64 + cf * 16 + (lane & 15);  // out col (in head)
      bpre[ks][cf] = *(const bf16x8*)(attb + l * 128 + ks * 32 + (lane >> 4) * 8);
    }

  // epilogue-1: e = exp(q + bq) (clamped); write swizzled qs[tok][feat] into
  // the freed smem (slot = (feat>>3) ^ (tok&31), bijective per row); per-head
  // row-sums into zq4[wn][tok] (each wave's 64 cols lie in ONE head).
  u16* qs = (u16*)smem;
#pragma unroll
  for (int rf = 0; rf < 8; rf++)
#pragma unroll
    for (int r = 0; r < 4; r++) {
      const int tok = wm * 128 + rf * 16 + (lane >> 4) * 4 + r;
      float rs = 0.f;
#pragma unroll
      for (int cf = 0; cf < 4; cf++) {
        const int f = wn * 64 + cf * 16 + (lane & 15);
        const float e = __expf(fminf(acc[rf][cf][r] + bq[n0 + f], 30.0f));
        qs[tok * 256 + ((((f >> 3) ^ (tok & 31)) << 3) | (f & 7))] = f2b(e);
        rs += e;
      }
      rs += __shfl_xor(rs, 1);
      rs += __shfl_xor(rs, 2);
      rs += __shfl_xor(rs, 4);
      rs += __shfl_xor(rs, 8);
      if ((lane & 15) == 0) zq4[wn][tok] = rs;
    }
  __syncthreads();

  // phase 2: y[tok, col] = sum_d P[tok, hl*128+d] * attT[bhh][l*128 + d].
  // A-frags from swizzled qs (chunk = hl*16 + ks*4 + q); B from bpre regs.
  f32x4 acc2[8][4];
#pragma unroll
  for (int i = 0; i < 8; i++)
#pragma unroll
    for (int j = 0; j < 4; j++) acc2[i][j] = zero;

#pragma unroll
  for (int ks = 0; ks < 4; ks++) {
    bf16x8 af[8];
#pragma unroll
    for (int rf = 0; rf < 8; rf++) {
      const int tok = wm * 128 + rf * 16 + (lane & 15);
      af[rf] = *(const bf16x8*)&qs[tok * 256 +
          ((((hl << 4) + (ks << 2) + (lane >> 4)) ^ (tok & 31)) << 3)];
    }
#pragma unroll
    for (int rf = 0; rf < 8; rf++)
#pragma unroll
      for (int cf = 0; cf < 4; cf++)
        acc2[rf][cf] = __builtin_amdgcn_mfma_f32_16x16x32_bf16(
            af[rf], bpre[ks][cf], acc2[rf][cf], 0, 0, 0);
  }

  // epilogue-2: out = x + y / zq  (fp32)
#pragma unroll
  for (int rf = 0; rf < 8; rf++)
#pragma unroll
    for (int r = 0; r < 4; r++) {
      const int tok = wm * 128 + rf * 16 + (lane >> 4) * 4 + r;
      const float zq =
          fmaxf(zq4[hl * 2][tok] + zq4[hl * 2 + 1][tok], 1e-30f);
      const size_t n = (size_t)(m0 + tok);
#pragma unroll
      for (int cf = 0; cf < 4; cf++) {
        const int f = wn * 64 + cf * 16 + (lane & 15);
        const size_t idx = n * 1024 + n0 + f;
        out[idx] = x[idx] + acc2[rf][cf][r] / zq;
      }
    }
}

// ----------------------------------------------------------------- launch
extern "C" void kernel_launch(void* const* d_in, const int* in_sizes, int n_in,
                              void* d_out, int out_size, void* d_ws, size_t ws_size,
                              hipStream_t stream) {
  const float* x = (const float*)d_in[0];
  const float* mask = (const float*)d_in[1];
  const float* Wq = (const float*)d_in[2];
  const float* bq = (const float*)d_in[3];
  const float* Wk = (const float*)d_in[4];
  const float* bk = (const float*)d_in[5];
  const float* Wv = (const float*)d_in[6];
  const float* bv = (const float*)d_in[7];
  const float* gamma = (const float*)d_in[8];
  const float* beta = (const float*)d_in[9];
  float* out = (float*)d_out;
  (void)d_ws; (void)ws_size;

  prep_kernel<<<dim3(16384 + 3072), 256, 0, stream>>>(x, gamma, beta, Wq, Wk, Wv);
  gemm_kv<<<dim3(512), 512, 0, stream>>>(bk, bv, mask);
  gemm_att<<<dim3(8, 32), 256, 0, stream>>>();
  attnorm_kernel<<<dim3(32, 8), 256, 0, stream>>>();
  gemm_qy<<<dim3(256), 512, 0, stream>>>(bq, x, out);
}